// Round 2
// baseline (1501.130 us; speedup 1.0000x reference)
//
#include <hip/hip_runtime.h>
#include <hip/hip_bf16.h>

#define BLK   256
#define NSAMP 558
#define NRAYS 2048
#define RESI  160
#define R2I   25600
#define R3I   4096000

// LDS float offsets for staged weights (row-major (din,dout) as in jnp)
#define AW1_O 0        // 15x32
#define AB1_O 480      // 32
#define AW2_O 512      // 32x32
#define AB2_O 1536     // 32
#define AW3_O 1568     // 32x4
#define AB3_O 1696     // 4
#define PW1_O 1700     // 12x16
#define PB1_O 1892     // 16
#define PW2_O 1908     // 16x16
#define PB2_O 2164     // 16
#define PW3_O 2180     // 16x16
#define PB3_O 2436     // 16
#define DW1_O 2452     // 54x16
#define DB1_O 3316     // 16
#define DW2_O 3332     // 16x16
#define DB2_O 3588     // 16
#define DW3_O 3604     // 16x16
#define DB3_O 3860     // 16
#define DW4_O 3876     // 16x3
#define DB4_O 3924     // 3
#define EMB_O 3928     // 39 (per-ray positional encoding of viewdir)
#define DEMB_O 3968    // 16 (db1 + emb @ dw1[15:54])
#define SCAN_O 3984    // 4 wave transmittance totals
#define RED_O  3988    // 4 waves x 5 partial sums
#define SW_FLOATS 4008

#define ACT_SHIFT_F (-4.5951198501345896f)
#define STEP_F 0.00625f   // STEPSIZE * VOXEL = 0.5 * 0.0125

template <typename T> __device__ __forceinline__ float ldv(const T* p, int i);
template <> __device__ __forceinline__ float ldv<float>(const float* p, int i) { return p[i]; }
template <> __device__ __forceinline__ float ldv<__hip_bfloat16>(const __hip_bfloat16* p, int i) {
    return __bfloat162float(p[i]);
}
template <typename T> __device__ __forceinline__ T cvt_out(float v);
template <> __device__ __forceinline__ float cvt_out<float>(float v) { return v; }
template <> __device__ __forceinline__ __hip_bfloat16 cvt_out<__hip_bfloat16>(float v) {
    return __float2bfloat16(v);
}

template <typename T>
struct KParams {
    const T *rays_o, *rays_d, *viewdirs, *grid;
    const T *aw1,*ab1,*aw2,*ab2,*aw3,*ab3;
    const T *pw1,*pb1,*pw2,*pb2,*pw3,*pb3;
    const T *dw1,*db1,*dw2,*db2,*dw3,*db3,*dw4,*db4;
    T *out;
    const int* flag;
    int want;   // 0 = f32 data, 1 = bf16 data
};

// ---- dtype detector: viewdirs rows are unit-norm under the TRUE dtype ----
__global__ void detect_dtype(const void* vd, int* flag) {
    if (threadIdx.x == 0 && blockIdx.x == 0) {
        const float* f = (const float*)vd;
        const __hip_bfloat16* h = (const __hip_bfloat16*)vd;
        float sf = 0.f, sb = 0.f;
        for (int r = 0; r < 8; ++r) {
            float a = f[r*3], b = f[r*3+1], c = f[r*3+2];
            float d = (a*a + b*b + c*c) - 1.f;
            sf += d*d;
            float a2 = __bfloat162float(h[r*3]);
            float b2 = __bfloat162float(h[r*3+1]);
            float c2 = __bfloat162float(h[r*3+2]);
            float d2 = (a2*a2 + b2*b2 + c2*c2) - 1.f;
            sb += d2*d2;
        }
        bool sf_ok = (sf == sf) && (sf < 1e30f);
        bool sb_ok = (sb == sb) && (sb < 1e30f);
        int fl = 0;
        if (sb_ok && (!sf_ok || sb < sf)) fl = 1;
        *flag = fl;
    }
}

template <typename T>
__device__ __forceinline__ void stage_w(float* dst, const T* src, int n, int tid) {
    for (int i = tid; i < n; i += BLK) dst[i] = ldv<T>(src, i);
}

template <typename T>
__global__ __launch_bounds__(BLK)
void nerf_fwd(KParams<T> P) {
    if (*P.flag != P.want) return;
    __shared__ float sw[SW_FLOATS];
    __shared__ float4 ssamp[NSAMP];
    const int tid = threadIdx.x;
    const int ray = blockIdx.x;

    // ---- stage weights -> f32 LDS ----
    stage_w(sw + AW1_O, P.aw1, 480, tid);
    stage_w(sw + AB1_O, P.ab1, 32, tid);
    stage_w(sw + AW2_O, P.aw2, 1024, tid);
    stage_w(sw + AB2_O, P.ab2, 32, tid);
    stage_w(sw + AW3_O, P.aw3, 128, tid);
    stage_w(sw + AB3_O, P.ab3, 4, tid);
    stage_w(sw + PW1_O, P.pw1, 192, tid);
    stage_w(sw + PB1_O, P.pb1, 16, tid);
    stage_w(sw + PW2_O, P.pw2, 256, tid);
    stage_w(sw + PB2_O, P.pb2, 16, tid);
    stage_w(sw + PW3_O, P.pw3, 256, tid);
    stage_w(sw + PB3_O, P.pb3, 16, tid);
    stage_w(sw + DW1_O, P.dw1, 864, tid);
    stage_w(sw + DB1_O, P.db1, 16, tid);
    stage_w(sw + DW2_O, P.dw2, 256, tid);
    stage_w(sw + DB2_O, P.db2, 16, tid);
    stage_w(sw + DW3_O, P.dw3, 256, tid);
    stage_w(sw + DB3_O, P.db3, 16, tid);
    stage_w(sw + DW4_O, P.dw4, 48, tid);
    stage_w(sw + DB4_O, P.db4, 3, tid);

    // ---- per-ray scalars (redundant per thread, cheap) ----
    const float ox = ldv<T>(P.rays_o, ray*3+0);
    const float oy = ldv<T>(P.rays_o, ray*3+1);
    const float oz = ldv<T>(P.rays_o, ray*3+2);
    const float dx = ldv<T>(P.rays_d, ray*3+0);
    const float dy = ldv<T>(P.rays_d, ray*3+1);
    const float dz = ldv<T>(P.rays_d, ray*3+2);
    const float vx = (dx == 0.f) ? 1e-6f : dx;
    const float vy = (dy == 0.f) ? 1e-6f : dy;
    const float vz = (dz == 0.f) ? 1e-6f : dz;
    const float rax = (1.f - ox) / vx, rbx = (-1.f - ox) / vx;
    const float ray_ = (1.f - oy) / vy, rby = (-1.f - oy) / vy;
    const float raz = (1.f - oz) / vz, rbz = (-1.f - oz) / vz;
    float tmin = fmaxf(fmaxf(fminf(rax, rbx), fminf(ray_, rby)), fminf(raz, rbz));
    float tmax = fminf(fminf(fmaxf(rax, rbx), fmaxf(ray_, rby)), fmaxf(raz, rbz));
    tmin = fminf(fmaxf(tmin, 0.05f), 3.5f);
    tmax = fminf(fmaxf(tmax, 0.05f), 3.5f);
    const bool mask_ray = (tmax <= tmin);
    const float norm_d = sqrtf(dx*dx + dy*dy + dz*dz);
    const float inv_nd = 1.f / norm_d;

    // ---- per-ray viewdir positional encoding into LDS ----
    if (tid < 39) {
        float v0 = ldv<T>(P.viewdirs, ray*3+0);
        float v1 = ldv<T>(P.viewdirs, ray*3+1);
        float v2 = ldv<T>(P.viewdirs, ray*3+2);
        float v3[3] = {v0, v1, v2};
        float val;
        if (tid < 3) val = v3[tid];
        else {
            int k = tid - 3;
            int l = k / 6, r = k % 6;
            float f = (float)(1 << l);
            val = (r < 3) ? sinf(v3[r]*f) : cosf(v3[r-3]*f);
        }
        sw[EMB_O + tid] = val;
    }
    __syncthreads();
    // fold emb through dw1 rows 15..53 (+db1) once per ray
    if (tid < 16) {
        float acc = sw[DB1_O + tid];
        for (int i = 0; i < 39; ++i)
            acc = fmaf(sw[EMB_O + i], sw[DW1_O + (15 + i)*16 + tid], acc);
        sw[DEMB_O + tid] = acc;
    }
    __syncthreads();

    // ---- per-sample compute ----
    for (int s = tid; s < NSAMP; s += BLK) {
        float stepw = STEP_F * (float)s;
        float it = fmaf(stepw, inv_nd, tmin);
        float px = fmaf(dx, it, ox);
        float py = fmaf(dy, it, oy);
        float pz = fmaf(dz, it, oz);
        bool inb = (!mask_ray) & (px >= -1.f) & (px <= 1.f) & (py >= -1.f) & (py <= 1.f)
                   & (pz >= -1.f) & (pz <= 1.f);
        float4 res = make_float4(0.f, 0.f, 0.f, 0.f);
        if (inb) {
            float gx = (px + 1.f) * 79.5f;
            float gy = (py + 1.f) * 79.5f;
            float gz = (pz + 1.f) * 79.5f;
            float fx0 = floorf(gx), fy0 = floorf(gy), fz0 = floorf(gz);
            float frx = gx - fx0, fry = gy - fy0, frz = gz - fz0;
            int x0 = min(max((int)fx0, 0), RESI-1); int x1 = min(x0+1, RESI-1);
            int y0 = min(max((int)fy0, 0), RESI-1); int y1 = min(y0+1, RESI-1);
            int z0 = min(max((int)fz0, 0), RESI-1); int z1 = min(z0+1, RESI-1);
            int bx0 = x0*R2I, bx1 = x1*R2I, by0 = y0*RESI, by1 = y1*RESI;
            int o000 = bx0+by0+z0, o001 = bx0+by0+z1, o010 = bx0+by1+z0, o011 = bx0+by1+z1;
            int o100 = bx1+by0+z0, o101 = bx1+by0+z1, o110 = bx1+by1+z0, o111 = bx1+by1+z1;
            float wx1 = frx, wx0 = 1.f-frx, wy1 = fry, wy0 = 1.f-fry, wz1 = frz, wz0 = 1.f-frz;
            float w000 = wx0*wy0*wz0, w001 = wx0*wy0*wz1, w010 = wx0*wy1*wz0, w011 = wx0*wy1*wz1;
            float w100 = wx1*wy0*wz0, w101 = wx1*wy0*wz1, w110 = wx1*wy1*wz0, w111 = wx1*wy1*wz1;
            float lat[12];
            #pragma unroll
            for (int c = 0; c < 12; ++c) {
                const T* g = P.grid + c*R3I;
                lat[c] = w000*ldv<T>(g,o000) + w001*ldv<T>(g,o001)
                       + w010*ldv<T>(g,o010) + w011*ldv<T>(g,o011)
                       + w100*ldv<T>(g,o100) + w101*ldv<T>(g,o101)
                       + w110*ldv<T>(g,o110) + w111*ldv<T>(g,o111);
            }
            // ---- attention MLP: [ind_norm(z,y,x), latent] -> 32 -> 32 -> 4 -> softmax[1]
            float a1[32];
            #pragma unroll
            for (int j = 0; j < 32; ++j) a1[j] = sw[AB1_O + j];
            {
                float in3[3] = {pz, py, px};
                #pragma unroll
                for (int i = 0; i < 3; ++i) {
                    float xi = in3[i];
                    #pragma unroll
                    for (int j = 0; j < 32; ++j) a1[j] = fmaf(xi, sw[AW1_O + i*32 + j], a1[j]);
                }
                #pragma unroll
                for (int i = 0; i < 12; ++i) {
                    float xi = lat[i];
                    #pragma unroll
                    for (int j = 0; j < 32; ++j) a1[j] = fmaf(xi, sw[AW1_O + (3+i)*32 + j], a1[j]);
                }
            }
            #pragma unroll
            for (int j = 0; j < 32; ++j) a1[j] = fmaxf(a1[j], 0.f);
            float a2[32];
            #pragma unroll
            for (int j = 0; j < 32; ++j) a2[j] = sw[AB2_O + j];
            #pragma unroll
            for (int i = 0; i < 32; ++i) {
                float xi = a1[i];
                #pragma unroll
                for (int j = 0; j < 32; ++j) a2[j] = fmaf(xi, sw[AW2_O + i*32 + j], a2[j]);
            }
            #pragma unroll
            for (int j = 0; j < 32; ++j) a2[j] = fmaxf(a2[j], 0.f);
            float lg[4];
            #pragma unroll
            for (int j = 0; j < 4; ++j) lg[j] = sw[AB3_O + j];
            #pragma unroll
            for (int i = 0; i < 32; ++i) {
                float xi = a2[i];
                #pragma unroll
                for (int j = 0; j < 4; ++j) lg[j] = fmaf(xi, sw[AW3_O + i*4 + j], lg[j]);
            }
            float m = fmaxf(fmaxf(lg[0], lg[1]), fmaxf(lg[2], lg[3]));
            float e0 = __expf(lg[0]-m), e1 = __expf(lg[1]-m), e2 = __expf(lg[2]-m), e3 = __expf(lg[3]-m);
            float att1 = e1 / (e0 + e1 + e2 + e3);
            // ---- pos MLP: latent -> 16 -> 16 -> 16
            float p1[16];
            #pragma unroll
            for (int j = 0; j < 16; ++j) p1[j] = sw[PB1_O + j];
            #pragma unroll
            for (int i = 0; i < 12; ++i) {
                float xi = lat[i];
                #pragma unroll
                for (int j = 0; j < 16; ++j) p1[j] = fmaf(xi, sw[PW1_O + i*16 + j], p1[j]);
            }
            #pragma unroll
            for (int j = 0; j < 16; ++j) p1[j] = fmaxf(p1[j], 0.f);
            float p2[16];
            #pragma unroll
            for (int j = 0; j < 16; ++j) p2[j] = sw[PB2_O + j];
            #pragma unroll
            for (int i = 0; i < 16; ++i) {
                float xi = p1[i];
                #pragma unroll
                for (int j = 0; j < 16; ++j) p2[j] = fmaf(xi, sw[PW2_O + i*16 + j], p2[j]);
            }
            #pragma unroll
            for (int j = 0; j < 16; ++j) p2[j] = fmaxf(p2[j], 0.f);
            float po[16];
            #pragma unroll
            for (int j = 0; j < 16; ++j) po[j] = sw[PB3_O + j];
            #pragma unroll
            for (int i = 0; i < 16; ++i) {
                float xi = p2[i];
                #pragma unroll
                for (int j = 0; j < 16; ++j) po[j] = fmaf(xi, sw[PW3_O + i*16 + j], po[j]);
            }
            // ---- dir MLP: [po[1:16], emb(folded)] -> 16 -> 16 -> 16 -> 3
            float d1[16];
            #pragma unroll
            for (int j = 0; j < 16; ++j) d1[j] = sw[DEMB_O + j];
            #pragma unroll
            for (int i = 0; i < 15; ++i) {
                float xi = po[i+1];
                #pragma unroll
                for (int j = 0; j < 16; ++j) d1[j] = fmaf(xi, sw[DW1_O + i*16 + j], d1[j]);
            }
            #pragma unroll
            for (int j = 0; j < 16; ++j) d1[j] = fmaxf(d1[j], 0.f);
            float d2[16];
            #pragma unroll
            for (int j = 0; j < 16; ++j) d2[j] = sw[DB2_O + j];
            #pragma unroll
            for (int i = 0; i < 16; ++i) {
                float xi = d1[i];
                #pragma unroll
                for (int j = 0; j < 16; ++j) d2[j] = fmaf(xi, sw[DW2_O + i*16 + j], d2[j]);
            }
            #pragma unroll
            for (int j = 0; j < 16; ++j) d2[j] = fmaxf(d2[j], 0.f);
            float d3[16];
            #pragma unroll
            for (int j = 0; j < 16; ++j) d3[j] = sw[DB3_O + j];
            #pragma unroll
            for (int i = 0; i < 16; ++i) {
                float xi = d2[i];
                #pragma unroll
                for (int j = 0; j < 16; ++j) d3[j] = fmaf(xi, sw[DW3_O + i*16 + j], d3[j]);
            }
            #pragma unroll
            for (int j = 0; j < 16; ++j) d3[j] = fmaxf(d3[j], 0.f);
            float rr[3];
            #pragma unroll
            for (int j = 0; j < 3; ++j) rr[j] = sw[DB4_O + j];
            #pragma unroll
            for (int i = 0; i < 16; ++i) {
                float xi = d3[i];
                #pragma unroll
                for (int j = 0; j < 3; ++j) rr[j] = fmaf(xi, sw[DW4_O + i*3 + j], rr[j]);
            }
            // ---- activation & alpha
            float dens = att1 * po[0];
            float xsh = dens + ACT_SHIFT_F;
            float sp = (xsh > 0.f) ? xsh + log1pf(__expf(-xsh)) : log1pf(__expf(xsh));
            res.x = 1.f - __expf(-sp * 0.5f);
            res.y = 1.f / (1.f + __expf(-att1 * rr[0]));
            res.z = 1.f / (1.f + __expf(-att1 * rr[1]));
            res.w = 1.f / (1.f + __expf(-att1 * rr[2]));
        }
        ssamp[s] = res;
    }
    __syncthreads();

    // ---- compositing: per-thread chunk of 3, then wave scan + cross-wave combine
    float lp = 1.f, cr = 0.f, cg = 0.f, cb = 0.f, cd = 0.f, ca = 0.f;
    if (tid < 186) {
        const float base_depth = tmin * norm_d;
        #pragma unroll
        for (int k = 0; k < 3; ++k) {
            int s = tid*3 + k;
            float4 sm = ssamp[s];
            float w = sm.x * lp;
            cr += w * sm.y;
            cg += w * sm.z;
            cb += w * sm.w;
            cd += w * (base_depth + STEP_F * (float)s);
            ca += w;
            lp *= fmaxf(1.f - sm.x, 1e-10f);
        }
    }
    const int lane = tid & 63, wid = tid >> 6;
    float pincl = lp;
    #pragma unroll
    for (int off = 1; off < 64; off <<= 1) {
        float v = __shfl_up(pincl, off, 64);
        if (lane >= off) pincl *= v;
    }
    float wtotal = __shfl(pincl, 63, 64);
    float excl = __shfl_up(pincl, 1, 64);
    if (lane == 0) excl = 1.f;
    if (lane == 0) sw[SCAN_O + wid] = wtotal;
    __syncthreads();
    float prefix = 1.f;
    for (int w = 0; w < wid; ++w) prefix *= sw[SCAN_O + w];
    float Tin = prefix * excl;
    cr *= Tin; cg *= Tin; cb *= Tin; cd *= Tin; ca *= Tin;
    #pragma unroll
    for (int off = 32; off > 0; off >>= 1) {
        cr += __shfl_down(cr, off, 64);
        cg += __shfl_down(cg, off, 64);
        cb += __shfl_down(cb, off, 64);
        cd += __shfl_down(cd, off, 64);
        ca += __shfl_down(ca, off, 64);
    }
    if (lane == 0) {
        sw[RED_O + wid*5 + 0] = cr;
        sw[RED_O + wid*5 + 1] = cg;
        sw[RED_O + wid*5 + 2] = cb;
        sw[RED_O + wid*5 + 3] = cd;
        sw[RED_O + wid*5 + 4] = ca;
    }
    __syncthreads();
    if (tid == 0) {
        float Tf = sw[SCAN_O+0] * sw[SCAN_O+1] * sw[SCAN_O+2] * sw[SCAN_O+3];
        float r = 0.f, g = 0.f, b = 0.f, dd = 0.f, aa = 0.f;
        #pragma unroll
        for (int w = 0; w < 4; ++w) {
            r  += sw[RED_O + w*5 + 0];
            g  += sw[RED_O + w*5 + 1];
            b  += sw[RED_O + w*5 + 2];
            dd += sw[RED_O + w*5 + 3];
            aa += sw[RED_O + w*5 + 4];
        }
        float depth_m = dd + Tf * 3.5f;
        T* o = P.out + ray*6;
        o[0] = cvt_out<T>(r + Tf);       // BG = 1.0
        o[1] = cvt_out<T>(g + Tf);
        o[2] = cvt_out<T>(b + Tf);
        o[3] = cvt_out<T>(depth_m);
        o[4] = cvt_out<T>(1.f / depth_m);
        o[5] = cvt_out<T>(aa);
    }
}

template <typename T>
static void fill_params(KParams<T>& P, void* const* d_in, void* d_out, const int* flag, int want) {
    P.rays_o   = (const T*)d_in[0];
    P.rays_d   = (const T*)d_in[1];
    P.viewdirs = (const T*)d_in[2];
    P.grid     = (const T*)d_in[3];
    P.aw1 = (const T*)d_in[4];  P.ab1 = (const T*)d_in[5];
    P.aw2 = (const T*)d_in[6];  P.ab2 = (const T*)d_in[7];
    P.aw3 = (const T*)d_in[8];  P.ab3 = (const T*)d_in[9];
    P.pw1 = (const T*)d_in[10]; P.pb1 = (const T*)d_in[11];
    P.pw2 = (const T*)d_in[12]; P.pb2 = (const T*)d_in[13];
    P.pw3 = (const T*)d_in[14]; P.pb3 = (const T*)d_in[15];
    P.dw1 = (const T*)d_in[16]; P.db1 = (const T*)d_in[17];
    P.dw2 = (const T*)d_in[18]; P.db2 = (const T*)d_in[19];
    P.dw3 = (const T*)d_in[20]; P.db3 = (const T*)d_in[21];
    P.dw4 = (const T*)d_in[22]; P.db4 = (const T*)d_in[23];
    P.out = (T*)d_out;
    P.flag = flag;
    P.want = want;
}

extern "C" void kernel_launch(void* const* d_in, const int* in_sizes, int n_in,
                              void* d_out, int out_size, void* d_ws, size_t ws_size,
                              hipStream_t stream) {
    int* flag = (int*)d_ws;
    hipLaunchKernelGGL(detect_dtype, dim3(1), dim3(64), 0, stream, d_in[2], flag);

    KParams<float> Pf;
    fill_params<float>(Pf, d_in, d_out, flag, 0);
    hipLaunchKernelGGL(nerf_fwd<float>, dim3(NRAYS), dim3(BLK), 0, stream, Pf);

    KParams<__hip_bfloat16> Pb;
    fill_params<__hip_bfloat16>(Pb, d_in, d_out, flag, 1);
    hipLaunchKernelGGL(nerf_fwd<__hip_bfloat16>, dim3(NRAYS), dim3(BLK), 0, stream, Pb);
}

// Round 3
// 1484.431 us; speedup vs baseline: 1.0112x; 1.0112x over previous
//
#include <hip/hip_runtime.h>
#include <hip/hip_bf16.h>

#define BLK   256
#define NSAMP 558
#define NRAYS 2048
#define RESI  160
#define R2I   25600
#define R3I   4096000
#define NTOT  (NRAYS * NSAMP)          // 1,142,784
#define SAMP_BLOCKS (NTOT / BLK)       // 4464 exact
#define RAYSTRIDE 32

#define ACT_SHIFT_F (-4.5951198501345896f)
#define STEP_F 0.00625f   // STEPSIZE * VOXEL = 0.5 * 0.0125

// ---------------- ws layout ----------------
// [0]            int flag
// [256]          float rayData[2048*32]   (262144 B)
// [262400]       float4 samp[2048*558]    (18,284,544 B)
#define RAYDATA_OFF 256
#define SAMP_OFF    (RAYDATA_OFF + NRAYS * RAYSTRIDE * 4)
#define WS_NEEDED   ((size_t)SAMP_OFF + (size_t)NTOT * 16)

template <typename T> __device__ __forceinline__ float ldv(const T* p, int i);
template <> __device__ __forceinline__ float ldv<float>(const float* p, int i) { return p[i]; }
template <> __device__ __forceinline__ float ldv<__hip_bfloat16>(const __hip_bfloat16* p, int i) {
    return __bfloat162float(p[i]);
}
template <typename T> __device__ __forceinline__ T cvt_out(float v);
template <> __device__ __forceinline__ float cvt_out<float>(float v) { return v; }
template <> __device__ __forceinline__ __hip_bfloat16 cvt_out<__hip_bfloat16>(float v) {
    return __float2bfloat16(v);
}

template <typename T>
struct KParams {
    const T *rays_o, *rays_d, *viewdirs, *grid;
    const T *aw1,*ab1,*aw2,*ab2,*aw3,*ab3;
    const T *pw1,*pb1,*pw2,*pb2,*pw3,*pb3;
    const T *dw1,*db1,*dw2,*db2,*dw3,*db3,*dw4,*db4;
    T *out;
    const int* flag;
    float* rayData;
    float4* samp;
    int want;
};

// ---- dtype detector: viewdirs rows are unit-norm under the TRUE dtype ----
__global__ void detect_dtype(const void* vd, int* flag) {
    if (threadIdx.x == 0 && blockIdx.x == 0) {
        const float* f = (const float*)vd;
        const __hip_bfloat16* h = (const __hip_bfloat16*)vd;
        float sf = 0.f, sb = 0.f;
        for (int r = 0; r < 8; ++r) {
            float a = f[r*3], b = f[r*3+1], c = f[r*3+2];
            float d = (a*a + b*b + c*c) - 1.f;
            sf += d*d;
            float a2 = __bfloat162float(h[r*3]);
            float b2 = __bfloat162float(h[r*3+1]);
            float c2 = __bfloat162float(h[r*3+2]);
            float d2 = (a2*a2 + b2*b2 + c2*c2) - 1.f;
            sb += d2*d2;
        }
        bool sf_ok = (sf == sf) && (sf < 1e30f);
        bool sb_ok = (sb == sb) && (sb < 1e30f);
        int fl = 0;
        if (sb_ok && (!sf_ok || sb < sf)) fl = 1;
        *flag = fl;
    }
}

// =============== Kernel 1: per-ray prep ===============
template <typename T>
__global__ __launch_bounds__(BLK)
void prep_k(KParams<T> P) {
    if (*P.flag != P.want) return;
    __shared__ float semb[BLK * 39];
    const int tid = threadIdx.x;
    const int ray = blockIdx.x * BLK + tid;
    if (ray >= NRAYS) return;
    const float ox = ldv<T>(P.rays_o, ray*3+0);
    const float oy = ldv<T>(P.rays_o, ray*3+1);
    const float oz = ldv<T>(P.rays_o, ray*3+2);
    const float dx = ldv<T>(P.rays_d, ray*3+0);
    const float dy = ldv<T>(P.rays_d, ray*3+1);
    const float dz = ldv<T>(P.rays_d, ray*3+2);
    const float vx = (dx == 0.f) ? 1e-6f : dx;
    const float vy = (dy == 0.f) ? 1e-6f : dy;
    const float vz = (dz == 0.f) ? 1e-6f : dz;
    const float rax = (1.f - ox) / vx, rbx = (-1.f - ox) / vx;
    const float ray_ = (1.f - oy) / vy, rby = (-1.f - oy) / vy;
    const float raz = (1.f - oz) / vz, rbz = (-1.f - oz) / vz;
    float tmin = fmaxf(fmaxf(fminf(rax, rbx), fminf(ray_, rby)), fminf(raz, rbz));
    float tmax = fminf(fminf(fmaxf(rax, rbx), fmaxf(ray_, rby)), fmaxf(raz, rbz));
    tmin = fminf(fmaxf(tmin, 0.05f), 3.5f);
    tmax = fminf(fmaxf(tmax, 0.05f), 3.5f);
    const bool mask_ray = (tmax <= tmin);
    const float norm_d = sqrtf(dx*dx + dy*dy + dz*dz);
    const float inv_nd = 1.f / norm_d;

    // viewdir positional encoding -> LDS (per-thread row, dynamic-indexable)
    {
        float v0 = ldv<T>(P.viewdirs, ray*3+0);
        float v1 = ldv<T>(P.viewdirs, ray*3+1);
        float v2 = ldv<T>(P.viewdirs, ray*3+2);
        float* e = semb + tid*39;
        e[0] = v0; e[1] = v1; e[2] = v2;
        #pragma unroll
        for (int l = 0; l < 6; ++l) {
            float f = (float)(1 << l);
            e[3 + l*6 + 0] = __sinf(v0*f);
            e[3 + l*6 + 1] = __sinf(v1*f);
            e[3 + l*6 + 2] = __sinf(v2*f);
            e[3 + l*6 + 3] = __cosf(v0*f);
            e[3 + l*6 + 4] = __cosf(v1*f);
            e[3 + l*6 + 5] = __cosf(v2*f);
        }
    }
    // fold emb through dw1 rows 15..53 (+db1)
    float acc[16];
    #pragma unroll
    for (int j = 0; j < 16; ++j) acc[j] = ldv<T>(P.db1, j);
    const float* e = semb + tid*39;
    for (int i = 0; i < 39; ++i) {
        float xi = e[i];
        #pragma unroll
        for (int j = 0; j < 16; ++j) acc[j] = fmaf(xi, ldv<T>(P.dw1, (15+i)*16 + j), acc[j]);
    }
    float* rd = P.rayData + ray * RAYSTRIDE;
    rd[0] = ox; rd[1] = oy; rd[2] = oz;
    rd[3] = dx; rd[4] = dy; rd[5] = dz;
    rd[6] = mask_ray ? __int_as_float(0x7fc00000) : tmin;  // NaN kills inb for all samples
    rd[7] = inv_nd;
    #pragma unroll
    for (int j = 0; j < 16; ++j) rd[8 + j] = acc[j];
    rd[24] = tmin * norm_d;   // base depth (finite even when masked; weights are 0 then)
}

// =============== Kernel 2: per-sample MLP chain ===============
// LDS float offsets
#define AW1_O 0
#define AB1_O 480
#define AW2_O 512
#define AB2_O 1536
#define AW3_O 1568
#define AB3_O 1696
#define PW1_O 1700
#define PB1_O 1892
#define PW2_O 1908
#define PB2_O 2164
#define PW3_O 2180
#define PB3_O 2436
#define DW1_O 2452   /* rows 0..14 only: 240 */
#define DW2_O 2692
#define DB2_O 2948
#define DW3_O 2964
#define DB3_O 3220
#define DW4_O 3236
#define DB4_O 3284
#define SW2_FLOATS 3287

template <typename T>
__device__ __forceinline__ void stage_w(float* dst, const T* src, int n, int tid) {
    for (int i = tid; i < n; i += BLK) dst[i] = ldv<T>(src, i);
}

template <typename T>
__global__ __launch_bounds__(BLK, 3)
void sample_k(KParams<T> P) {
    if (*P.flag != P.want) return;
    __shared__ float sw[SW2_FLOATS];
    const int tid = threadIdx.x;
    stage_w(sw + AW1_O, P.aw1, 480, tid);
    stage_w(sw + AB1_O, P.ab1, 32, tid);
    stage_w(sw + AW2_O, P.aw2, 1024, tid);
    stage_w(sw + AB2_O, P.ab2, 32, tid);
    stage_w(sw + AW3_O, P.aw3, 128, tid);
    stage_w(sw + AB3_O, P.ab3, 4, tid);
    stage_w(sw + PW1_O, P.pw1, 192, tid);
    stage_w(sw + PB1_O, P.pb1, 16, tid);
    stage_w(sw + PW2_O, P.pw2, 256, tid);
    stage_w(sw + PB2_O, P.pb2, 16, tid);
    stage_w(sw + PW3_O, P.pw3, 256, tid);
    stage_w(sw + PB3_O, P.pb3, 16, tid);
    stage_w(sw + DW1_O, P.dw1, 240, tid);
    stage_w(sw + DW2_O, P.dw2, 256, tid);
    stage_w(sw + DB2_O, P.db2, 16, tid);
    stage_w(sw + DW3_O, P.dw3, 256, tid);
    stage_w(sw + DB3_O, P.db3, 16, tid);
    stage_w(sw + DW4_O, P.dw4, 48, tid);
    stage_w(sw + DB4_O, P.db4, 3, tid);
    __syncthreads();

    const int idx = blockIdx.x * BLK + tid;     // grid is exact: idx < NTOT
    const int ray = idx / NSAMP;
    const int s   = idx - ray * NSAMP;
    const float* rd = P.rayData + ray * RAYSTRIDE;
    const float tmin = rd[6], inv_nd = rd[7];
    const float it = fmaf(STEP_F * (float)s, inv_nd, tmin);
    const float px = fmaf(rd[3], it, rd[0]);
    const float py = fmaf(rd[4], it, rd[1]);
    const float pz = fmaf(rd[5], it, rd[2]);
    bool inb = (px >= -1.f) & (px <= 1.f) & (py >= -1.f) & (py <= 1.f)
             & (pz >= -1.f) & (pz <= 1.f);     // NaN tmin -> false
    float4 res = make_float4(0.f, 0.f, 0.f, 0.f);
    if (inb) {
        float gx = (px + 1.f) * 79.5f;
        float gy = (py + 1.f) * 79.5f;
        float gz = (pz + 1.f) * 79.5f;
        float fx0 = floorf(gx), fy0 = floorf(gy), fz0 = floorf(gz);
        float frx = gx - fx0, fry = gy - fy0, frz = gz - fz0;
        int x0 = min(max((int)fx0, 0), RESI-1); int x1 = min(x0+1, RESI-1);
        int y0 = min(max((int)fy0, 0), RESI-1); int y1 = min(y0+1, RESI-1);
        int z0 = min(max((int)fz0, 0), RESI-1); int z1 = min(z0+1, RESI-1);
        int bx0 = x0*R2I, bx1 = x1*R2I, by0 = y0*RESI, by1 = y1*RESI;
        int o000 = bx0+by0+z0, o001 = bx0+by0+z1, o010 = bx0+by1+z0, o011 = bx0+by1+z1;
        int o100 = bx1+by0+z0, o101 = bx1+by0+z1, o110 = bx1+by1+z0, o111 = bx1+by1+z1;
        float wx0 = 1.f-frx, wy0 = 1.f-fry, wz0 = 1.f-frz;
        float w000 = wx0*wy0*wz0, w001 = wx0*wy0*frz, w010 = wx0*fry*wz0, w011 = wx0*fry*frz;
        float w100 = frx*wy0*wz0, w101 = frx*wy0*frz, w110 = frx*fry*wz0, w111 = frx*fry*frz;
        float lat[12];
        #pragma unroll
        for (int c = 0; c < 12; ++c) {
            const T* g = P.grid + c*R3I;
            lat[c] = w000*ldv<T>(g,o000) + w001*ldv<T>(g,o001)
                   + w010*ldv<T>(g,o010) + w011*ldv<T>(g,o011)
                   + w100*ldv<T>(g,o100) + w101*ldv<T>(g,o101)
                   + w110*ldv<T>(g,o110) + w111*ldv<T>(g,o111);
        }
        // ---- attention MLP ----
        float a1[32];
        #pragma unroll
        for (int j = 0; j < 32; ++j) a1[j] = sw[AB1_O + j];
        {
            float in3[3] = {pz, py, px};
            #pragma unroll
            for (int i = 0; i < 3; ++i) {
                float xi = in3[i];
                #pragma unroll
                for (int j = 0; j < 32; ++j) a1[j] = fmaf(xi, sw[AW1_O + i*32 + j], a1[j]);
            }
            #pragma unroll
            for (int i = 0; i < 12; ++i) {
                float xi = lat[i];
                #pragma unroll
                for (int j = 0; j < 32; ++j) a1[j] = fmaf(xi, sw[AW1_O + (3+i)*32 + j], a1[j]);
            }
        }
        #pragma unroll
        for (int j = 0; j < 32; ++j) a1[j] = fmaxf(a1[j], 0.f);
        // hidden2 in chunks of 8 to keep live set small
        float lg[4];
        #pragma unroll
        for (int k = 0; k < 4; ++k) lg[k] = sw[AB3_O + k];
        #pragma unroll
        for (int c = 0; c < 4; ++c) {
            float t[8];
            #pragma unroll
            for (int j = 0; j < 8; ++j) t[j] = sw[AB2_O + c*8 + j];
            #pragma unroll
            for (int i = 0; i < 32; ++i) {
                float xi = a1[i];
                #pragma unroll
                for (int j = 0; j < 8; ++j) t[j] = fmaf(xi, sw[AW2_O + i*32 + c*8 + j], t[j]);
            }
            #pragma unroll
            for (int j = 0; j < 8; ++j) {
                float tv = fmaxf(t[j], 0.f);
                #pragma unroll
                for (int k = 0; k < 4; ++k) lg[k] = fmaf(tv, sw[AW3_O + (c*8+j)*4 + k], lg[k]);
            }
        }
        float m = fmaxf(fmaxf(lg[0], lg[1]), fmaxf(lg[2], lg[3]));
        float e0 = __expf(lg[0]-m), e1 = __expf(lg[1]-m), e2 = __expf(lg[2]-m), e3 = __expf(lg[3]-m);
        float att1 = e1 / (e0 + e1 + e2 + e3);
        // ---- pos MLP ----
        float p1[16];
        #pragma unroll
        for (int j = 0; j < 16; ++j) p1[j] = sw[PB1_O + j];
        #pragma unroll
        for (int i = 0; i < 12; ++i) {
            float xi = lat[i];
            #pragma unroll
            for (int j = 0; j < 16; ++j) p1[j] = fmaf(xi, sw[PW1_O + i*16 + j], p1[j]);
        }
        #pragma unroll
        for (int j = 0; j < 16; ++j) p1[j] = fmaxf(p1[j], 0.f);
        float p2[16];
        #pragma unroll
        for (int j = 0; j < 16; ++j) p2[j] = sw[PB2_O + j];
        #pragma unroll
        for (int i = 0; i < 16; ++i) {
            float xi = p1[i];
            #pragma unroll
            for (int j = 0; j < 16; ++j) p2[j] = fmaf(xi, sw[PW2_O + i*16 + j], p2[j]);
        }
        #pragma unroll
        for (int j = 0; j < 16; ++j) p2[j] = fmaxf(p2[j], 0.f);
        float po[16];
        #pragma unroll
        for (int j = 0; j < 16; ++j) po[j] = sw[PB3_O + j];
        #pragma unroll
        for (int i = 0; i < 16; ++i) {
            float xi = p2[i];
            #pragma unroll
            for (int j = 0; j < 16; ++j) po[j] = fmaf(xi, sw[PW3_O + i*16 + j], po[j]);
        }
        // ---- dir MLP ----
        float d1[16];
        #pragma unroll
        for (int j = 0; j < 16; ++j) d1[j] = rd[8 + j];   // demb (db1 + emb fold)
        #pragma unroll
        for (int i = 0; i < 15; ++i) {
            float xi = po[i+1];
            #pragma unroll
            for (int j = 0; j < 16; ++j) d1[j] = fmaf(xi, sw[DW1_O + i*16 + j], d1[j]);
        }
        #pragma unroll
        for (int j = 0; j < 16; ++j) d1[j] = fmaxf(d1[j], 0.f);
        float d2[16];
        #pragma unroll
        for (int j = 0; j < 16; ++j) d2[j] = sw[DB2_O + j];
        #pragma unroll
        for (int i = 0; i < 16; ++i) {
            float xi = d1[i];
            #pragma unroll
            for (int j = 0; j < 16; ++j) d2[j] = fmaf(xi, sw[DW2_O + i*16 + j], d2[j]);
        }
        #pragma unroll
        for (int j = 0; j < 16; ++j) d2[j] = fmaxf(d2[j], 0.f);
        float d3[16];
        #pragma unroll
        for (int j = 0; j < 16; ++j) d3[j] = sw[DB3_O + j];
        #pragma unroll
        for (int i = 0; i < 16; ++i) {
            float xi = d2[i];
            #pragma unroll
            for (int j = 0; j < 16; ++j) d3[j] = fmaf(xi, sw[DW3_O + i*16 + j], d3[j]);
        }
        #pragma unroll
        for (int j = 0; j < 16; ++j) d3[j] = fmaxf(d3[j], 0.f);
        float rr[3];
        #pragma unroll
        for (int k = 0; k < 3; ++k) rr[k] = sw[DB4_O + k];
        #pragma unroll
        for (int i = 0; i < 16; ++i) {
            float xi = d3[i];
            #pragma unroll
            for (int k = 0; k < 3; ++k) rr[k] = fmaf(xi, sw[DW4_O + i*3 + k], rr[k]);
        }
        float dens = att1 * po[0];
        float xsh = dens + ACT_SHIFT_F;
        float sp = (xsh > 0.f) ? xsh + log1pf(__expf(-xsh)) : log1pf(__expf(xsh));
        res.x = 1.f - __expf(-sp * 0.5f);
        res.y = 1.f / (1.f + __expf(-att1 * rr[0]));
        res.z = 1.f / (1.f + __expf(-att1 * rr[1]));
        res.w = 1.f / (1.f + __expf(-att1 * rr[2]));
    }
    P.samp[idx] = res;
}

// =============== Kernel 3: per-ray composite (one wave per ray) ===============
template <typename T>
__global__ __launch_bounds__(64)
void composite_k(KParams<T> P) {
    if (*P.flag != P.want) return;
    const int ray = blockIdx.x;
    const int lane = threadIdx.x;
    const float base_depth = P.rayData[ray * RAYSTRIDE + 24];
    const float4* sp = P.samp + ray * NSAMP;
    float lp = 1.f, cr = 0.f, cg = 0.f, cb = 0.f, cd = 0.f, ca = 0.f;
    #pragma unroll
    for (int k = 0; k < 9; ++k) {
        int s = lane * 9 + k;
        if (s < NSAMP) {
            float4 sm = sp[s];
            float w = sm.x * lp;
            cr += w * sm.y;
            cg += w * sm.z;
            cb += w * sm.w;
            cd += w * (base_depth + STEP_F * (float)s);
            ca += w;
            lp *= fmaxf(1.f - sm.x, 1e-10f);
        }
    }
    float pincl = lp;
    #pragma unroll
    for (int off = 1; off < 64; off <<= 1) {
        float v = __shfl_up(pincl, off, 64);
        if (lane >= off) pincl *= v;
    }
    float Tf = __shfl(pincl, 63, 64);
    float excl = __shfl_up(pincl, 1, 64);
    if (lane == 0) excl = 1.f;
    cr *= excl; cg *= excl; cb *= excl; cd *= excl; ca *= excl;
    #pragma unroll
    for (int off = 32; off > 0; off >>= 1) {
        cr += __shfl_down(cr, off, 64);
        cg += __shfl_down(cg, off, 64);
        cb += __shfl_down(cb, off, 64);
        cd += __shfl_down(cd, off, 64);
        ca += __shfl_down(ca, off, 64);
    }
    if (lane == 0) {
        float depth_m = cd + Tf * 3.5f;
        T* o = P.out + ray*6;
        o[0] = cvt_out<T>(cr + Tf);
        o[1] = cvt_out<T>(cg + Tf);
        o[2] = cvt_out<T>(cb + Tf);
        o[3] = cvt_out<T>(depth_m);
        o[4] = cvt_out<T>(1.f / depth_m);
        o[5] = cvt_out<T>(ca);
    }
}

// =============== Fallback: round-2 fused kernel (used only if ws too small) ===============
#define FAW1_O 0
#define FAB1_O 480
#define FAW2_O 512
#define FAB2_O 1536
#define FAW3_O 1568
#define FAB3_O 1696
#define FPW1_O 1700
#define FPB1_O 1892
#define FPW2_O 1908
#define FPB2_O 2164
#define FPW3_O 2180
#define FPB3_O 2436
#define FDW1_O 2452
#define FDB1_O 3316
#define FDW2_O 3332
#define FDB2_O 3588
#define FDW3_O 3604
#define FDB3_O 3860
#define FDW4_O 3876
#define FDB4_O 3924
#define FEMB_O 3928
#define FDEMB_O 3968
#define FSCAN_O 3984
#define FRED_O  3988
#define FSW_FLOATS 4008

template <typename T>
__global__ __launch_bounds__(BLK)
void nerf_fused(KParams<T> P) {
    if (*P.flag != P.want) return;
    __shared__ float sw[FSW_FLOATS];
    __shared__ float4 ssamp[NSAMP];
    const int tid = threadIdx.x;
    const int ray = blockIdx.x;
    stage_w(sw + FAW1_O, P.aw1, 480, tid);
    stage_w(sw + FAB1_O, P.ab1, 32, tid);
    stage_w(sw + FAW2_O, P.aw2, 1024, tid);
    stage_w(sw + FAB2_O, P.ab2, 32, tid);
    stage_w(sw + FAW3_O, P.aw3, 128, tid);
    stage_w(sw + FAB3_O, P.ab3, 4, tid);
    stage_w(sw + FPW1_O, P.pw1, 192, tid);
    stage_w(sw + FPB1_O, P.pb1, 16, tid);
    stage_w(sw + FPW2_O, P.pw2, 256, tid);
    stage_w(sw + FPB2_O, P.pb2, 16, tid);
    stage_w(sw + FPW3_O, P.pw3, 256, tid);
    stage_w(sw + FPB3_O, P.pb3, 16, tid);
    stage_w(sw + FDW1_O, P.dw1, 864, tid);
    stage_w(sw + FDB1_O, P.db1, 16, tid);
    stage_w(sw + FDW2_O, P.dw2, 256, tid);
    stage_w(sw + FDB2_O, P.db2, 16, tid);
    stage_w(sw + FDW3_O, P.dw3, 256, tid);
    stage_w(sw + FDB3_O, P.db3, 16, tid);
    stage_w(sw + FDW4_O, P.dw4, 48, tid);
    stage_w(sw + FDB4_O, P.db4, 3, tid);
    const float ox = ldv<T>(P.rays_o, ray*3+0);
    const float oy = ldv<T>(P.rays_o, ray*3+1);
    const float oz = ldv<T>(P.rays_o, ray*3+2);
    const float dx = ldv<T>(P.rays_d, ray*3+0);
    const float dy = ldv<T>(P.rays_d, ray*3+1);
    const float dz = ldv<T>(P.rays_d, ray*3+2);
    const float vx = (dx == 0.f) ? 1e-6f : dx;
    const float vy = (dy == 0.f) ? 1e-6f : dy;
    const float vz = (dz == 0.f) ? 1e-6f : dz;
    const float rax = (1.f - ox) / vx, rbx = (-1.f - ox) / vx;
    const float ray_ = (1.f - oy) / vy, rby = (-1.f - oy) / vy;
    const float raz = (1.f - oz) / vz, rbz = (-1.f - oz) / vz;
    float tmin = fmaxf(fmaxf(fminf(rax, rbx), fminf(ray_, rby)), fminf(raz, rbz));
    float tmax = fminf(fminf(fmaxf(rax, rbx), fmaxf(ray_, rby)), fmaxf(raz, rbz));
    tmin = fminf(fmaxf(tmin, 0.05f), 3.5f);
    tmax = fminf(fmaxf(tmax, 0.05f), 3.5f);
    const bool mask_ray = (tmax <= tmin);
    const float norm_d = sqrtf(dx*dx + dy*dy + dz*dz);
    const float inv_nd = 1.f / norm_d;
    if (tid < 39) {
        float v0 = ldv<T>(P.viewdirs, ray*3+0);
        float v1 = ldv<T>(P.viewdirs, ray*3+1);
        float v2 = ldv<T>(P.viewdirs, ray*3+2);
        float v3[3] = {v0, v1, v2};
        float val;
        if (tid < 3) val = v3[tid];
        else {
            int k = tid - 3;
            int l = k / 6, r = k % 6;
            float f = (float)(1 << l);
            val = (r < 3) ? sinf(v3[r]*f) : cosf(v3[r-3]*f);
        }
        sw[FEMB_O + tid] = val;
    }
    __syncthreads();
    if (tid < 16) {
        float acc = sw[FDB1_O + tid];
        for (int i = 0; i < 39; ++i)
            acc = fmaf(sw[FEMB_O + i], sw[FDW1_O + (15 + i)*16 + tid], acc);
        sw[FDEMB_O + tid] = acc;
    }
    __syncthreads();
    for (int s = tid; s < NSAMP; s += BLK) {
        float it = fmaf(STEP_F * (float)s, inv_nd, tmin);
        float px = fmaf(dx, it, ox);
        float py = fmaf(dy, it, oy);
        float pz = fmaf(dz, it, oz);
        bool inb = (!mask_ray) & (px >= -1.f) & (px <= 1.f) & (py >= -1.f) & (py <= 1.f)
                   & (pz >= -1.f) & (pz <= 1.f);
        float4 res = make_float4(0.f, 0.f, 0.f, 0.f);
        if (inb) {
            float gx = (px + 1.f) * 79.5f;
            float gy = (py + 1.f) * 79.5f;
            float gz = (pz + 1.f) * 79.5f;
            float fx0 = floorf(gx), fy0 = floorf(gy), fz0 = floorf(gz);
            float frx = gx - fx0, fry = gy - fy0, frz = gz - fz0;
            int x0 = min(max((int)fx0, 0), RESI-1); int x1 = min(x0+1, RESI-1);
            int y0 = min(max((int)fy0, 0), RESI-1); int y1 = min(y0+1, RESI-1);
            int z0 = min(max((int)fz0, 0), RESI-1); int z1 = min(z0+1, RESI-1);
            int bx0 = x0*R2I, bx1 = x1*R2I, by0 = y0*RESI, by1 = y1*RESI;
            int o000 = bx0+by0+z0, o001 = bx0+by0+z1, o010 = bx0+by1+z0, o011 = bx0+by1+z1;
            int o100 = bx1+by0+z0, o101 = bx1+by0+z1, o110 = bx1+by1+z0, o111 = bx1+by1+z1;
            float wx0 = 1.f-frx, wy0 = 1.f-fry, wz0 = 1.f-frz;
            float w000 = wx0*wy0*wz0, w001 = wx0*wy0*frz, w010 = wx0*fry*wz0, w011 = wx0*fry*frz;
            float w100 = frx*wy0*wz0, w101 = frx*wy0*frz, w110 = frx*fry*wz0, w111 = frx*fry*frz;
            float lat[12];
            #pragma unroll
            for (int c = 0; c < 12; ++c) {
                const T* g = P.grid + c*R3I;
                lat[c] = w000*ldv<T>(g,o000) + w001*ldv<T>(g,o001)
                       + w010*ldv<T>(g,o010) + w011*ldv<T>(g,o011)
                       + w100*ldv<T>(g,o100) + w101*ldv<T>(g,o101)
                       + w110*ldv<T>(g,o110) + w111*ldv<T>(g,o111);
            }
            float a1[32];
            #pragma unroll
            for (int j = 0; j < 32; ++j) a1[j] = sw[FAB1_O + j];
            {
                float in3[3] = {pz, py, px};
                #pragma unroll
                for (int i = 0; i < 3; ++i) {
                    float xi = in3[i];
                    #pragma unroll
                    for (int j = 0; j < 32; ++j) a1[j] = fmaf(xi, sw[FAW1_O + i*32 + j], a1[j]);
                }
                #pragma unroll
                for (int i = 0; i < 12; ++i) {
                    float xi = lat[i];
                    #pragma unroll
                    for (int j = 0; j < 32; ++j) a1[j] = fmaf(xi, sw[FAW1_O + (3+i)*32 + j], a1[j]);
                }
            }
            #pragma unroll
            for (int j = 0; j < 32; ++j) a1[j] = fmaxf(a1[j], 0.f);
            float lg[4];
            #pragma unroll
            for (int k = 0; k < 4; ++k) lg[k] = sw[FAB3_O + k];
            #pragma unroll
            for (int c = 0; c < 4; ++c) {
                float t[8];
                #pragma unroll
                for (int j = 0; j < 8; ++j) t[j] = sw[FAB2_O + c*8 + j];
                #pragma unroll
                for (int i = 0; i < 32; ++i) {
                    float xi = a1[i];
                    #pragma unroll
                    for (int j = 0; j < 8; ++j) t[j] = fmaf(xi, sw[FAW2_O + i*32 + c*8 + j], t[j]);
                }
                #pragma unroll
                for (int j = 0; j < 8; ++j) {
                    float tv = fmaxf(t[j], 0.f);
                    #pragma unroll
                    for (int k = 0; k < 4; ++k) lg[k] = fmaf(tv, sw[FAW3_O + (c*8+j)*4 + k], lg[k]);
                }
            }
            float m = fmaxf(fmaxf(lg[0], lg[1]), fmaxf(lg[2], lg[3]));
            float e0 = __expf(lg[0]-m), e1 = __expf(lg[1]-m), e2 = __expf(lg[2]-m), e3 = __expf(lg[3]-m);
            float att1 = e1 / (e0 + e1 + e2 + e3);
            float p1[16];
            #pragma unroll
            for (int j = 0; j < 16; ++j) p1[j] = sw[FPB1_O + j];
            #pragma unroll
            for (int i = 0; i < 12; ++i) {
                float xi = lat[i];
                #pragma unroll
                for (int j = 0; j < 16; ++j) p1[j] = fmaf(xi, sw[FPW1_O + i*16 + j], p1[j]);
            }
            #pragma unroll
            for (int j = 0; j < 16; ++j) p1[j] = fmaxf(p1[j], 0.f);
            float p2[16];
            #pragma unroll
            for (int j = 0; j < 16; ++j) p2[j] = sw[FPB2_O + j];
            #pragma unroll
            for (int i = 0; i < 16; ++i) {
                float xi = p1[i];
                #pragma unroll
                for (int j = 0; j < 16; ++j) p2[j] = fmaf(xi, sw[FPW2_O + i*16 + j], p2[j]);
            }
            #pragma unroll
            for (int j = 0; j < 16; ++j) p2[j] = fmaxf(p2[j], 0.f);
            float po[16];
            #pragma unroll
            for (int j = 0; j < 16; ++j) po[j] = sw[FPB3_O + j];
            #pragma unroll
            for (int i = 0; i < 16; ++i) {
                float xi = p2[i];
                #pragma unroll
                for (int j = 0; j < 16; ++j) po[j] = fmaf(xi, sw[FPW3_O + i*16 + j], po[j]);
            }
            float d1[16];
            #pragma unroll
            for (int j = 0; j < 16; ++j) d1[j] = sw[FDEMB_O + j];
            #pragma unroll
            for (int i = 0; i < 15; ++i) {
                float xi = po[i+1];
                #pragma unroll
                for (int j = 0; j < 16; ++j) d1[j] = fmaf(xi, sw[FDW1_O + i*16 + j], d1[j]);
            }
            #pragma unroll
            for (int j = 0; j < 16; ++j) d1[j] = fmaxf(d1[j], 0.f);
            float d2[16];
            #pragma unroll
            for (int j = 0; j < 16; ++j) d2[j] = sw[FDB2_O + j];
            #pragma unroll
            for (int i = 0; i < 16; ++i) {
                float xi = d1[i];
                #pragma unroll
                for (int j = 0; j < 16; ++j) d2[j] = fmaf(xi, sw[FDW2_O + i*16 + j], d2[j]);
            }
            #pragma unroll
            for (int j = 0; j < 16; ++j) d2[j] = fmaxf(d2[j], 0.f);
            float d3[16];
            #pragma unroll
            for (int j = 0; j < 16; ++j) d3[j] = sw[FDB3_O + j];
            #pragma unroll
            for (int i = 0; i < 16; ++i) {
                float xi = d2[i];
                #pragma unroll
                for (int j = 0; j < 16; ++j) d3[j] = fmaf(xi, sw[FDW3_O + i*16 + j], d3[j]);
            }
            #pragma unroll
            for (int j = 0; j < 16; ++j) d3[j] = fmaxf(d3[j], 0.f);
            float rr[3];
            #pragma unroll
            for (int k = 0; k < 3; ++k) rr[k] = sw[FDB4_O + k];
            #pragma unroll
            for (int i = 0; i < 16; ++i) {
                float xi = d3[i];
                #pragma unroll
                for (int k = 0; k < 3; ++k) rr[k] = fmaf(xi, sw[FDW4_O + i*3 + k], rr[k]);
            }
            float dens = att1 * po[0];
            float xsh = dens + ACT_SHIFT_F;
            float sp2 = (xsh > 0.f) ? xsh + log1pf(__expf(-xsh)) : log1pf(__expf(xsh));
            res.x = 1.f - __expf(-sp2 * 0.5f);
            res.y = 1.f / (1.f + __expf(-att1 * rr[0]));
            res.z = 1.f / (1.f + __expf(-att1 * rr[1]));
            res.w = 1.f / (1.f + __expf(-att1 * rr[2]));
        }
        ssamp[s] = res;
    }
    __syncthreads();
    float lp = 1.f, cr = 0.f, cg = 0.f, cb = 0.f, cd = 0.f, ca = 0.f;
    if (tid < 186) {
        const float base_depth = tmin * norm_d;
        #pragma unroll
        for (int k = 0; k < 3; ++k) {
            int s = tid*3 + k;
            float4 sm = ssamp[s];
            float w = sm.x * lp;
            cr += w * sm.y;
            cg += w * sm.z;
            cb += w * sm.w;
            cd += w * (base_depth + STEP_F * (float)s);
            ca += w;
            lp *= fmaxf(1.f - sm.x, 1e-10f);
        }
    }
    const int lane = tid & 63, wid = tid >> 6;
    float pincl = lp;
    #pragma unroll
    for (int off = 1; off < 64; off <<= 1) {
        float v = __shfl_up(pincl, off, 64);
        if (lane >= off) pincl *= v;
    }
    float wtotal = __shfl(pincl, 63, 64);
    float excl = __shfl_up(pincl, 1, 64);
    if (lane == 0) excl = 1.f;
    if (lane == 0) sw[FSCAN_O + wid] = wtotal;
    __syncthreads();
    float prefix = 1.f;
    for (int w = 0; w < wid; ++w) prefix *= sw[FSCAN_O + w];
    float Tin = prefix * excl;
    cr *= Tin; cg *= Tin; cb *= Tin; cd *= Tin; ca *= Tin;
    #pragma unroll
    for (int off = 32; off > 0; off >>= 1) {
        cr += __shfl_down(cr, off, 64);
        cg += __shfl_down(cg, off, 64);
        cb += __shfl_down(cb, off, 64);
        cd += __shfl_down(cd, off, 64);
        ca += __shfl_down(ca, off, 64);
    }
    if (lane == 0) {
        sw[FRED_O + wid*5 + 0] = cr;
        sw[FRED_O + wid*5 + 1] = cg;
        sw[FRED_O + wid*5 + 2] = cb;
        sw[FRED_O + wid*5 + 3] = cd;
        sw[FRED_O + wid*5 + 4] = ca;
    }
    __syncthreads();
    if (tid == 0) {
        float Tf = sw[FSCAN_O+0] * sw[FSCAN_O+1] * sw[FSCAN_O+2] * sw[FSCAN_O+3];
        float r = 0.f, g = 0.f, b = 0.f, dd = 0.f, aa = 0.f;
        #pragma unroll
        for (int w = 0; w < 4; ++w) {
            r  += sw[FRED_O + w*5 + 0];
            g  += sw[FRED_O + w*5 + 1];
            b  += sw[FRED_O + w*5 + 2];
            dd += sw[FRED_O + w*5 + 3];
            aa += sw[FRED_O + w*5 + 4];
        }
        float depth_m = dd + Tf * 3.5f;
        T* o = P.out + ray*6;
        o[0] = cvt_out<T>(r + Tf);
        o[1] = cvt_out<T>(g + Tf);
        o[2] = cvt_out<T>(b + Tf);
        o[3] = cvt_out<T>(depth_m);
        o[4] = cvt_out<T>(1.f / depth_m);
        o[5] = cvt_out<T>(aa);
    }
}

template <typename T>
static void fill_params(KParams<T>& P, void* const* d_in, void* d_out, void* d_ws, int want) {
    P.rays_o   = (const T*)d_in[0];
    P.rays_d   = (const T*)d_in[1];
    P.viewdirs = (const T*)d_in[2];
    P.grid     = (const T*)d_in[3];
    P.aw1 = (const T*)d_in[4];  P.ab1 = (const T*)d_in[5];
    P.aw2 = (const T*)d_in[6];  P.ab2 = (const T*)d_in[7];
    P.aw3 = (const T*)d_in[8];  P.ab3 = (const T*)d_in[9];
    P.pw1 = (const T*)d_in[10]; P.pb1 = (const T*)d_in[11];
    P.pw2 = (const T*)d_in[12]; P.pb2 = (const T*)d_in[13];
    P.pw3 = (const T*)d_in[14]; P.pb3 = (const T*)d_in[15];
    P.dw1 = (const T*)d_in[16]; P.db1 = (const T*)d_in[17];
    P.dw2 = (const T*)d_in[18]; P.db2 = (const T*)d_in[19];
    P.dw3 = (const T*)d_in[20]; P.db3 = (const T*)d_in[21];
    P.dw4 = (const T*)d_in[22]; P.db4 = (const T*)d_in[23];
    P.out = (T*)d_out;
    P.flag = (const int*)d_ws;
    P.rayData = (float*)((char*)d_ws + RAYDATA_OFF);
    P.samp = (float4*)((char*)d_ws + SAMP_OFF);
    P.want = want;
}

extern "C" void kernel_launch(void* const* d_in, const int* in_sizes, int n_in,
                              void* d_out, int out_size, void* d_ws, size_t ws_size,
                              hipStream_t stream) {
    int* flag = (int*)d_ws;
    hipLaunchKernelGGL(detect_dtype, dim3(1), dim3(64), 0, stream, d_in[2], flag);

    KParams<float> Pf;
    fill_params<float>(Pf, d_in, d_out, d_ws, 0);
    KParams<__hip_bfloat16> Pb;
    fill_params<__hip_bfloat16>(Pb, d_in, d_out, d_ws, 1);

    if (ws_size >= WS_NEEDED) {
        hipLaunchKernelGGL(prep_k<float>, dim3((NRAYS + BLK - 1)/BLK), dim3(BLK), 0, stream, Pf);
        hipLaunchKernelGGL(prep_k<__hip_bfloat16>, dim3((NRAYS + BLK - 1)/BLK), dim3(BLK), 0, stream, Pb);
        hipLaunchKernelGGL(sample_k<float>, dim3(SAMP_BLOCKS), dim3(BLK), 0, stream, Pf);
        hipLaunchKernelGGL(sample_k<__hip_bfloat16>, dim3(SAMP_BLOCKS), dim3(BLK), 0, stream, Pb);
        hipLaunchKernelGGL(composite_k<float>, dim3(NRAYS), dim3(64), 0, stream, Pf);
        hipLaunchKernelGGL(composite_k<__hip_bfloat16>, dim3(NRAYS), dim3(64), 0, stream, Pb);
    } else {
        hipLaunchKernelGGL(nerf_fused<float>, dim3(NRAYS), dim3(BLK), 0, stream, Pf);
        hipLaunchKernelGGL(nerf_fused<__hip_bfloat16>, dim3(NRAYS), dim3(BLK), 0, stream, Pb);
    }
}

// Round 5
// 1299.007 us; speedup vs baseline: 1.1556x; 1.1427x over previous
//
#include <hip/hip_runtime.h>
#include <hip/hip_bf16.h>

#define BLK   256
#define NSAMP 558
#define NRAYS 2048
#define RESI  160
#define R2I   25600
#define R3I   4096000
#define NTOT  (NRAYS * NSAMP)          // 1,142,784
#define SAMP_BLOCKS (NTOT / BLK)       // 4464 exact
#define RAYSTRIDE 32
#define NVOX  4096000                  // 160^3
#define TG_BLOCKS (NVOX / BLK)         // 16000 exact

#define ACT_SHIFT_F (-4.5951198501345896f)
#define STEP_F 0.00625f   // STEPSIZE * VOXEL

// ---------------- ws layout ----------------
// [0]          int flag
// [256]        float rayData[2048*32]            (262,144 B)
// [262400]     float4 samp[2048*558]             (18,284,544 B)
// [18546944]   ushort tgrid[160^3 * 16]          (131,072,000 B)   [big path only]
#define RAYDATA_OFF 256
#define SAMP_OFF    (RAYDATA_OFF + NRAYS * RAYSTRIDE * 4)
#define TG_OFF      (SAMP_OFF + (size_t)NTOT * 16)
#define WS_BIG      (TG_OFF + (size_t)NVOX * 32)

template <typename T> __device__ __forceinline__ float ldv(const T* p, int i);
template <> __device__ __forceinline__ float ldv<float>(const float* p, int i) { return p[i]; }
template <> __device__ __forceinline__ float ldv<__hip_bfloat16>(const __hip_bfloat16* p, int i) {
    return __bfloat162float(p[i]);
}
template <typename T> __device__ __forceinline__ T cvt_out(float v);
template <> __device__ __forceinline__ float cvt_out<float>(float v) { return v; }
template <> __device__ __forceinline__ __hip_bfloat16 cvt_out<__hip_bfloat16>(float v) {
    return __float2bfloat16(v);
}
__device__ __forceinline__ float b2f(unsigned short u) {
    union { float f; unsigned int i; } c; c.i = ((unsigned int)u) << 16; return c.f;
}
__device__ __forceinline__ unsigned short f2b(float v) {
    __hip_bfloat16 h = __float2bfloat16(v);
    unsigned short u;
    __builtin_memcpy(&u, &h, sizeof(u));
    return u;
}

template <typename T>
struct KParams {
    const T *rays_o, *rays_d, *viewdirs, *grid;
    const T *aw1,*ab1,*aw2,*ab2,*aw3,*ab3;
    const T *pw1,*pb1,*pw2,*pb2,*pw3,*pb3;
    const T *dw1,*db1,*dw2,*db2,*dw3,*db3,*dw4,*db4;
    T *out;
    const int* flag;
    float* rayData;
    float4* samp;
    unsigned short* tgrid;
    int want;
};

// ---- dtype detector: viewdirs rows are unit-norm under the TRUE dtype ----
__global__ void detect_dtype(const void* vd, int* flag) {
    if (threadIdx.x == 0 && blockIdx.x == 0) {
        const float* f = (const float*)vd;
        const __hip_bfloat16* h = (const __hip_bfloat16*)vd;
        float sf = 0.f, sb = 0.f;
        for (int r = 0; r < 8; ++r) {
            float a = f[r*3], b = f[r*3+1], c = f[r*3+2];
            float d = (a*a + b*b + c*c) - 1.f;
            sf += d*d;
            float a2 = __bfloat162float(h[r*3]);
            float b2 = __bfloat162float(h[r*3+1]);
            float c2 = __bfloat162float(h[r*3+2]);
            float d2 = (a2*a2 + b2*b2 + c2*c2) - 1.f;
            sb += d2*d2;
        }
        bool sf_ok = (sf == sf) && (sf < 1e30f);
        bool sb_ok = (sb == sb) && (sb < 1e30f);
        int fl = 0;
        if (sb_ok && (!sf_ok || sb < sf)) fl = 1;
        *flag = fl;
    }
}

// =============== Transpose: (12, X, Y, Z) -> voxel-major [X][Y][Z][16ch] bf16 ===============
template <typename T>
__global__ __launch_bounds__(BLK)
void transpose_k(KParams<T> P) {
    if (*P.flag != P.want) return;
    const int i = blockIdx.x * BLK + threadIdx.x;   // voxel index, z fastest (matches grid flatten)
    unsigned short r[16];
    #pragma unroll
    for (int c = 0; c < 12; ++c) r[c] = f2b(ldv<T>(P.grid, c * R3I + i));
    #pragma unroll
    for (int c = 12; c < 16; ++c) r[c] = 0;
    uint4* dst = (uint4*)(P.tgrid + (size_t)i * 16);
    uint4 w0, w1;
    w0.x = (unsigned int)r[0] | ((unsigned int)r[1] << 16);
    w0.y = (unsigned int)r[2] | ((unsigned int)r[3] << 16);
    w0.z = (unsigned int)r[4] | ((unsigned int)r[5] << 16);
    w0.w = (unsigned int)r[6] | ((unsigned int)r[7] << 16);
    w1.x = (unsigned int)r[8] | ((unsigned int)r[9] << 16);
    w1.y = (unsigned int)r[10] | ((unsigned int)r[11] << 16);
    w1.z = 0; w1.w = 0;
    dst[0] = w0; dst[1] = w1;
}

// =============== Kernel 1: per-ray prep ===============
template <typename T>
__global__ __launch_bounds__(BLK)
void prep_k(KParams<T> P) {
    if (*P.flag != P.want) return;
    __shared__ float semb[BLK * 39];
    const int tid = threadIdx.x;
    const int ray = blockIdx.x * BLK + tid;
    if (ray >= NRAYS) return;
    const float ox = ldv<T>(P.rays_o, ray*3+0);
    const float oy = ldv<T>(P.rays_o, ray*3+1);
    const float oz = ldv<T>(P.rays_o, ray*3+2);
    const float dx = ldv<T>(P.rays_d, ray*3+0);
    const float dy = ldv<T>(P.rays_d, ray*3+1);
    const float dz = ldv<T>(P.rays_d, ray*3+2);
    const float vx = (dx == 0.f) ? 1e-6f : dx;
    const float vy = (dy == 0.f) ? 1e-6f : dy;
    const float vz = (dz == 0.f) ? 1e-6f : dz;
    const float rax = (1.f - ox) / vx, rbx = (-1.f - ox) / vx;
    const float ray_ = (1.f - oy) / vy, rby = (-1.f - oy) / vy;
    const float raz = (1.f - oz) / vz, rbz = (-1.f - oz) / vz;
    float tmin = fmaxf(fmaxf(fminf(rax, rbx), fminf(ray_, rby)), fminf(raz, rbz));
    float tmax = fminf(fminf(fmaxf(rax, rbx), fmaxf(ray_, rby)), fmaxf(raz, rbz));
    tmin = fminf(fmaxf(tmin, 0.05f), 3.5f);
    tmax = fminf(fmaxf(tmax, 0.05f), 3.5f);
    const bool mask_ray = (tmax <= tmin);
    const float norm_d = sqrtf(dx*dx + dy*dy + dz*dz);
    const float inv_nd = 1.f / norm_d;
    {
        float v0 = ldv<T>(P.viewdirs, ray*3+0);
        float v1 = ldv<T>(P.viewdirs, ray*3+1);
        float v2 = ldv<T>(P.viewdirs, ray*3+2);
        float* e = semb + tid*39;
        e[0] = v0; e[1] = v1; e[2] = v2;
        #pragma unroll
        for (int l = 0; l < 6; ++l) {
            float f = (float)(1 << l);
            e[3 + l*6 + 0] = __sinf(v0*f);
            e[3 + l*6 + 1] = __sinf(v1*f);
            e[3 + l*6 + 2] = __sinf(v2*f);
            e[3 + l*6 + 3] = __cosf(v0*f);
            e[3 + l*6 + 4] = __cosf(v1*f);
            e[3 + l*6 + 5] = __cosf(v2*f);
        }
    }
    float acc[16];
    #pragma unroll
    for (int j = 0; j < 16; ++j) acc[j] = ldv<T>(P.db1, j);
    const float* e = semb + tid*39;
    for (int i = 0; i < 39; ++i) {
        float xi = e[i];
        #pragma unroll
        for (int j = 0; j < 16; ++j) acc[j] = fmaf(xi, ldv<T>(P.dw1, (15+i)*16 + j), acc[j]);
    }
    float* rd = P.rayData + ray * RAYSTRIDE;
    rd[0] = ox; rd[1] = oy; rd[2] = oz;
    rd[3] = dx; rd[4] = dy; rd[5] = dz;
    rd[6] = mask_ray ? __int_as_float(0x7fc00000) : tmin;
    rd[7] = inv_nd;
    #pragma unroll
    for (int j = 0; j < 16; ++j) rd[8 + j] = acc[j];
    rd[24] = tmin * norm_d;
}

// =============== shared LDS weight layout for sample kernels ===============
#define AW1_O 0
#define AB1_O 480
#define AW2_O 512
#define AB2_O 1536
#define AW3_O 1568
#define AB3_O 1696
#define PW1_O 1700
#define PB1_O 1892
#define PW2_O 1908
#define PB2_O 2164
#define PW3_O 2180
#define PB3_O 2436
#define DW1_O 2452   /* rows 0..14 only: 240 */
#define DW2_O 2692
#define DB2_O 2948
#define DW3_O 2964
#define DB3_O 3220
#define DW4_O 3236
#define DB4_O 3284
#define SW2_FLOATS 3287

template <typename T>
__device__ __forceinline__ void stage_w(float* dst, const T* src, int n, int tid) {
    for (int i = tid; i < n; i += BLK) dst[i] = ldv<T>(src, i);
}

template <typename T>
__device__ __forceinline__ void stage_all(float* sw, const KParams<T>& P, int tid) {
    stage_w(sw + AW1_O, P.aw1, 480, tid);
    stage_w(sw + AB1_O, P.ab1, 32, tid);
    stage_w(sw + AW2_O, P.aw2, 1024, tid);
    stage_w(sw + AB2_O, P.ab2, 32, tid);
    stage_w(sw + AW3_O, P.aw3, 128, tid);
    stage_w(sw + AB3_O, P.ab3, 4, tid);
    stage_w(sw + PW1_O, P.pw1, 192, tid);
    stage_w(sw + PB1_O, P.pb1, 16, tid);
    stage_w(sw + PW2_O, P.pw2, 256, tid);
    stage_w(sw + PB2_O, P.pb2, 16, tid);
    stage_w(sw + PW3_O, P.pw3, 256, tid);
    stage_w(sw + PB3_O, P.pb3, 16, tid);
    stage_w(sw + DW1_O, P.dw1, 240, tid);
    stage_w(sw + DW2_O, P.dw2, 256, tid);
    stage_w(sw + DB2_O, P.db2, 16, tid);
    stage_w(sw + DW3_O, P.dw3, 256, tid);
    stage_w(sw + DB3_O, P.db3, 16, tid);
    stage_w(sw + DW4_O, P.dw4, 48, tid);
    stage_w(sw + DB4_O, P.db4, 3, tid);
}

// Full MLP chain given lat[12] and position; returns float4(alpha, r, g, b)
__device__ __forceinline__ float4 mlp_chain(const float* sw, const float* rd,
                                            const float* lat, float px, float py, float pz) {
    float a1[32];
    #pragma unroll
    for (int j = 0; j < 32; ++j) a1[j] = sw[AB1_O + j];
    {
        float in3[3] = {pz, py, px};
        #pragma unroll
        for (int i = 0; i < 3; ++i) {
            float xi = in3[i];
            #pragma unroll
            for (int j = 0; j < 32; ++j) a1[j] = fmaf(xi, sw[AW1_O + i*32 + j], a1[j]);
        }
        #pragma unroll
        for (int i = 0; i < 12; ++i) {
            float xi = lat[i];
            #pragma unroll
            for (int j = 0; j < 32; ++j) a1[j] = fmaf(xi, sw[AW1_O + (3+i)*32 + j], a1[j]);
        }
    }
    #pragma unroll
    for (int j = 0; j < 32; ++j) a1[j] = fmaxf(a1[j], 0.f);
    float lg[4];
    #pragma unroll
    for (int k = 0; k < 4; ++k) lg[k] = sw[AB3_O + k];
    #pragma unroll
    for (int c = 0; c < 4; ++c) {
        float t[8];
        #pragma unroll
        for (int j = 0; j < 8; ++j) t[j] = sw[AB2_O + c*8 + j];
        #pragma unroll
        for (int i = 0; i < 32; ++i) {
            float xi = a1[i];
            #pragma unroll
            for (int j = 0; j < 8; ++j) t[j] = fmaf(xi, sw[AW2_O + i*32 + c*8 + j], t[j]);
        }
        #pragma unroll
        for (int j = 0; j < 8; ++j) {
            float tv = fmaxf(t[j], 0.f);
            #pragma unroll
            for (int k = 0; k < 4; ++k) lg[k] = fmaf(tv, sw[AW3_O + (c*8+j)*4 + k], lg[k]);
        }
    }
    float m = fmaxf(fmaxf(lg[0], lg[1]), fmaxf(lg[2], lg[3]));
    float e0 = __expf(lg[0]-m), e1 = __expf(lg[1]-m), e2 = __expf(lg[2]-m), e3 = __expf(lg[3]-m);
    float att1 = e1 / (e0 + e1 + e2 + e3);
    float p1[16];
    #pragma unroll
    for (int j = 0; j < 16; ++j) p1[j] = sw[PB1_O + j];
    #pragma unroll
    for (int i = 0; i < 12; ++i) {
        float xi = lat[i];
        #pragma unroll
        for (int j = 0; j < 16; ++j) p1[j] = fmaf(xi, sw[PW1_O + i*16 + j], p1[j]);
    }
    #pragma unroll
    for (int j = 0; j < 16; ++j) p1[j] = fmaxf(p1[j], 0.f);
    float p2[16];
    #pragma unroll
    for (int j = 0; j < 16; ++j) p2[j] = sw[PB2_O + j];
    #pragma unroll
    for (int i = 0; i < 16; ++i) {
        float xi = p1[i];
        #pragma unroll
        for (int j = 0; j < 16; ++j) p2[j] = fmaf(xi, sw[PW2_O + i*16 + j], p2[j]);
    }
    #pragma unroll
    for (int j = 0; j < 16; ++j) p2[j] = fmaxf(p2[j], 0.f);
    float po[16];
    #pragma unroll
    for (int j = 0; j < 16; ++j) po[j] = sw[PB3_O + j];
    #pragma unroll
    for (int i = 0; i < 16; ++i) {
        float xi = p2[i];
        #pragma unroll
        for (int j = 0; j < 16; ++j) po[j] = fmaf(xi, sw[PW3_O + i*16 + j], po[j]);
    }
    float d1[16];
    #pragma unroll
    for (int j = 0; j < 16; ++j) d1[j] = rd[8 + j];
    #pragma unroll
    for (int i = 0; i < 15; ++i) {
        float xi = po[i+1];
        #pragma unroll
        for (int j = 0; j < 16; ++j) d1[j] = fmaf(xi, sw[DW1_O + i*16 + j], d1[j]);
    }
    #pragma unroll
    for (int j = 0; j < 16; ++j) d1[j] = fmaxf(d1[j], 0.f);
    float d2[16];
    #pragma unroll
    for (int j = 0; j < 16; ++j) d2[j] = sw[DB2_O + j];
    #pragma unroll
    for (int i = 0; i < 16; ++i) {
        float xi = d1[i];
        #pragma unroll
        for (int j = 0; j < 16; ++j) d2[j] = fmaf(xi, sw[DW2_O + i*16 + j], d2[j]);
    }
    #pragma unroll
    for (int j = 0; j < 16; ++j) d2[j] = fmaxf(d2[j], 0.f);
    float d3[16];
    #pragma unroll
    for (int j = 0; j < 16; ++j) d3[j] = sw[DB3_O + j];
    #pragma unroll
    for (int i = 0; i < 16; ++i) {
        float xi = d2[i];
        #pragma unroll
        for (int j = 0; j < 16; ++j) d3[j] = fmaf(xi, sw[DW3_O + i*16 + j], d3[j]);
    }
    #pragma unroll
    for (int j = 0; j < 16; ++j) d3[j] = fmaxf(d3[j], 0.f);
    float rr[3];
    #pragma unroll
    for (int k = 0; k < 3; ++k) rr[k] = sw[DB4_O + k];
    #pragma unroll
    for (int i = 0; i < 16; ++i) {
        float xi = d3[i];
        #pragma unroll
        for (int k = 0; k < 3; ++k) rr[k] = fmaf(xi, sw[DW4_O + i*3 + k], rr[k]);
    }
    float dens = att1 * po[0];
    float xsh = dens + ACT_SHIFT_F;
    float sp = (xsh > 0.f) ? xsh + log1pf(__expf(-xsh)) : log1pf(__expf(xsh));
    float4 res;
    res.x = 1.f - __expf(-sp * 0.5f);
    res.y = 1.f / (1.f + __expf(-att1 * rr[0]));
    res.z = 1.f / (1.f + __expf(-att1 * rr[1]));
    res.w = 1.f / (1.f + __expf(-att1 * rr[2]));
    return res;
}

// =============== Kernel 2 (big path): per-sample, AoS transposed grid ===============
template <typename T>
__global__ __launch_bounds__(BLK, 3)
void sample_tg_k(KParams<T> P) {
    if (*P.flag != P.want) return;
    __shared__ float sw[SW2_FLOATS];
    const int tid = threadIdx.x;
    stage_all(sw, P, tid);
    __syncthreads();

    const int idx = blockIdx.x * BLK + tid;
    const int ray = idx / NSAMP;
    const int s   = idx - ray * NSAMP;
    const float* rd = P.rayData + ray * RAYSTRIDE;
    const float tmin = rd[6], inv_nd = rd[7];
    const float it = fmaf(STEP_F * (float)s, inv_nd, tmin);
    const float px = fmaf(rd[3], it, rd[0]);
    const float py = fmaf(rd[4], it, rd[1]);
    const float pz = fmaf(rd[5], it, rd[2]);
    bool inb = (px >= -1.f) & (px <= 1.f) & (py >= -1.f) & (py <= 1.f)
             & (pz >= -1.f) & (pz <= 1.f);
    float4 res = make_float4(0.f, 0.f, 0.f, 0.f);
    if (inb) {
        float gx = (px + 1.f) * 79.5f;
        float gy = (py + 1.f) * 79.5f;
        float gz = (pz + 1.f) * 79.5f;
        float fx0 = floorf(gx), fy0 = floorf(gy), fz0 = floorf(gz);
        float frx = gx - fx0, fry = gy - fy0, frz = gz - fz0;
        int x0 = min(max((int)fx0, 0), RESI-1); int x1 = min(x0+1, RESI-1);
        int y0 = min(max((int)fy0, 0), RESI-1); int y1 = min(y0+1, RESI-1);
        int z0 = min(max((int)fz0, 0), RESI-1); int z1 = min(z0+1, RESI-1);
        int bx0 = x0*R2I, bx1 = x1*R2I, by0 = y0*RESI, by1 = y1*RESI;
        float wx0 = 1.f-frx, wy0 = 1.f-fry, wz0 = 1.f-frz;
        float wc[8] = { wx0*wy0*wz0, wx0*wy0*frz, wx0*fry*wz0, wx0*fry*frz,
                        frx*wy0*wz0, frx*wy0*frz, frx*fry*wz0, frx*fry*frz };
        int oc[8] = { (bx0+by0+z0)*16, (bx0+by0+z1)*16, (bx0+by1+z0)*16, (bx0+by1+z1)*16,
                      (bx1+by0+z0)*16, (bx1+by0+z1)*16, (bx1+by1+z0)*16, (bx1+by1+z1)*16 };
        float lat[12];
        #pragma unroll
        for (int c = 0; c < 12; ++c) lat[c] = 0.f;
        #pragma unroll
        for (int k = 0; k < 8; ++k) {
            const ushort4* p = (const ushort4*)(P.tgrid + oc[k]);
            ushort4 u0 = p[0], u1 = p[1], u2 = p[2];
            float w = wc[k];
            lat[0]  = fmaf(w, b2f(u0.x), lat[0]);
            lat[1]  = fmaf(w, b2f(u0.y), lat[1]);
            lat[2]  = fmaf(w, b2f(u0.z), lat[2]);
            lat[3]  = fmaf(w, b2f(u0.w), lat[3]);
            lat[4]  = fmaf(w, b2f(u1.x), lat[4]);
            lat[5]  = fmaf(w, b2f(u1.y), lat[5]);
            lat[6]  = fmaf(w, b2f(u1.z), lat[6]);
            lat[7]  = fmaf(w, b2f(u1.w), lat[7]);
            lat[8]  = fmaf(w, b2f(u2.x), lat[8]);
            lat[9]  = fmaf(w, b2f(u2.y), lat[9]);
            lat[10] = fmaf(w, b2f(u2.z), lat[10]);
            lat[11] = fmaf(w, b2f(u2.w), lat[11]);
        }
        res = mlp_chain(sw, rd, lat, px, py, pz);
    }
    P.samp[idx] = res;
}

// =============== Kernel 2 (mid fallback): scattered gather from original grid ===============
template <typename T>
__global__ __launch_bounds__(BLK, 3)
void sample_k(KParams<T> P) {
    if (*P.flag != P.want) return;
    __shared__ float sw[SW2_FLOATS];
    const int tid = threadIdx.x;
    stage_all(sw, P, tid);
    __syncthreads();

    const int idx = blockIdx.x * BLK + tid;
    const int ray = idx / NSAMP;
    const int s   = idx - ray * NSAMP;
    const float* rd = P.rayData + ray * RAYSTRIDE;
    const float tmin = rd[6], inv_nd = rd[7];
    const float it = fmaf(STEP_F * (float)s, inv_nd, tmin);
    const float px = fmaf(rd[3], it, rd[0]);
    const float py = fmaf(rd[4], it, rd[1]);
    const float pz = fmaf(rd[5], it, rd[2]);
    bool inb = (px >= -1.f) & (px <= 1.f) & (py >= -1.f) & (py <= 1.f)
             & (pz >= -1.f) & (pz <= 1.f);
    float4 res = make_float4(0.f, 0.f, 0.f, 0.f);
    if (inb) {
        float gx = (px + 1.f) * 79.5f;
        float gy = (py + 1.f) * 79.5f;
        float gz = (pz + 1.f) * 79.5f;
        float fx0 = floorf(gx), fy0 = floorf(gy), fz0 = floorf(gz);
        float frx = gx - fx0, fry = gy - fy0, frz = gz - fz0;
        int x0 = min(max((int)fx0, 0), RESI-1); int x1 = min(x0+1, RESI-1);
        int y0 = min(max((int)fy0, 0), RESI-1); int y1 = min(y0+1, RESI-1);
        int z0 = min(max((int)fz0, 0), RESI-1); int z1 = min(z0+1, RESI-1);
        int bx0 = x0*R2I, bx1 = x1*R2I, by0 = y0*RESI, by1 = y1*RESI;
        int o000 = bx0+by0+z0, o001 = bx0+by0+z1, o010 = bx0+by1+z0, o011 = bx0+by1+z1;
        int o100 = bx1+by0+z0, o101 = bx1+by0+z1, o110 = bx1+by1+z0, o111 = bx1+by1+z1;
        float wx0 = 1.f-frx, wy0 = 1.f-fry, wz0 = 1.f-frz;
        float w000 = wx0*wy0*wz0, w001 = wx0*wy0*frz, w010 = wx0*fry*wz0, w011 = wx0*fry*frz;
        float w100 = frx*wy0*wz0, w101 = frx*wy0*frz, w110 = frx*fry*wz0, w111 = frx*fry*frz;
        float lat[12];
        #pragma unroll
        for (int c = 0; c < 12; ++c) {
            const T* g = P.grid + c*R3I;
            lat[c] = w000*ldv<T>(g,o000) + w001*ldv<T>(g,o001)
                   + w010*ldv<T>(g,o010) + w011*ldv<T>(g,o011)
                   + w100*ldv<T>(g,o100) + w101*ldv<T>(g,o101)
                   + w110*ldv<T>(g,o110) + w111*ldv<T>(g,o111);
        }
        res = mlp_chain(sw, rd, lat, px, py, pz);
    }
    P.samp[idx] = res;
}

// =============== Kernel 3: per-ray composite (one wave per ray) ===============
template <typename T>
__global__ __launch_bounds__(64)
void composite_k(KParams<T> P) {
    if (*P.flag != P.want) return;
    const int ray = blockIdx.x;
    const int lane = threadIdx.x;
    const float base_depth = P.rayData[ray * RAYSTRIDE + 24];
    const float4* sp = P.samp + ray * NSAMP;
    float lp = 1.f, cr = 0.f, cg = 0.f, cb = 0.f, cd = 0.f, ca = 0.f;
    #pragma unroll
    for (int k = 0; k < 9; ++k) {
        int s = lane * 9 + k;
        if (s < NSAMP) {
            float4 sm = sp[s];
            float w = sm.x * lp;
            cr += w * sm.y;
            cg += w * sm.z;
            cb += w * sm.w;
            cd += w * (base_depth + STEP_F * (float)s);
            ca += w;
            lp *= fmaxf(1.f - sm.x, 1e-10f);
        }
    }
    float pincl = lp;
    #pragma unroll
    for (int off = 1; off < 64; off <<= 1) {
        float v = __shfl_up(pincl, off, 64);
        if (lane >= off) pincl *= v;
    }
    float Tf = __shfl(pincl, 63, 64);
    float excl = __shfl_up(pincl, 1, 64);
    if (lane == 0) excl = 1.f;
    cr *= excl; cg *= excl; cb *= excl; cd *= excl; ca *= excl;
    #pragma unroll
    for (int off = 32; off > 0; off >>= 1) {
        cr += __shfl_down(cr, off, 64);
        cg += __shfl_down(cg, off, 64);
        cb += __shfl_down(cb, off, 64);
        cd += __shfl_down(cd, off, 64);
        ca += __shfl_down(ca, off, 64);
    }
    if (lane == 0) {
        float depth_m = cd + Tf * 3.5f;
        T* o = P.out + ray*6;
        o[0] = cvt_out<T>(cr + Tf);
        o[1] = cvt_out<T>(cg + Tf);
        o[2] = cvt_out<T>(cb + Tf);
        o[3] = cvt_out<T>(depth_m);
        o[4] = cvt_out<T>(1.f / depth_m);
        o[5] = cvt_out<T>(ca);
    }
}

template <typename T>
static void fill_params(KParams<T>& P, void* const* d_in, void* d_out, void* d_ws, int want) {
    P.rays_o   = (const T*)d_in[0];
    P.rays_d   = (const T*)d_in[1];
    P.viewdirs = (const T*)d_in[2];
    P.grid     = (const T*)d_in[3];
    P.aw1 = (const T*)d_in[4];  P.ab1 = (const T*)d_in[5];
    P.aw2 = (const T*)d_in[6];  P.ab2 = (const T*)d_in[7];
    P.aw3 = (const T*)d_in[8];  P.ab3 = (const T*)d_in[9];
    P.pw1 = (const T*)d_in[10]; P.pb1 = (const T*)d_in[11];
    P.pw2 = (const T*)d_in[12]; P.pb2 = (const T*)d_in[13];
    P.pw3 = (const T*)d_in[14]; P.pb3 = (const T*)d_in[15];
    P.dw1 = (const T*)d_in[16]; P.db1 = (const T*)d_in[17];
    P.dw2 = (const T*)d_in[18]; P.db2 = (const T*)d_in[19];
    P.dw3 = (const T*)d_in[20]; P.db3 = (const T*)d_in[21];
    P.dw4 = (const T*)d_in[22]; P.db4 = (const T*)d_in[23];
    P.out = (T*)d_out;
    P.flag = (const int*)d_ws;
    P.rayData = (float*)((char*)d_ws + RAYDATA_OFF);
    P.samp = (float4*)((char*)d_ws + SAMP_OFF);
    P.tgrid = (unsigned short*)((char*)d_ws + TG_OFF);
    P.want = want;
}

extern "C" void kernel_launch(void* const* d_in, const int* in_sizes, int n_in,
                              void* d_out, int out_size, void* d_ws, size_t ws_size,
                              hipStream_t stream) {
    int* flag = (int*)d_ws;
    hipLaunchKernelGGL(detect_dtype, dim3(1), dim3(64), 0, stream, d_in[2], flag);

    KParams<float> Pf;
    fill_params<float>(Pf, d_in, d_out, d_ws, 0);
    KParams<__hip_bfloat16> Pb;
    fill_params<__hip_bfloat16>(Pb, d_in, d_out, d_ws, 1);

    hipLaunchKernelGGL(prep_k<float>, dim3((NRAYS + BLK - 1)/BLK), dim3(BLK), 0, stream, Pf);
    hipLaunchKernelGGL(prep_k<__hip_bfloat16>, dim3((NRAYS + BLK - 1)/BLK), dim3(BLK), 0, stream, Pb);

    if (ws_size >= WS_BIG) {
        hipLaunchKernelGGL(transpose_k<float>, dim3(TG_BLOCKS), dim3(BLK), 0, stream, Pf);
        hipLaunchKernelGGL(transpose_k<__hip_bfloat16>, dim3(TG_BLOCKS), dim3(BLK), 0, stream, Pb);
        hipLaunchKernelGGL(sample_tg_k<float>, dim3(SAMP_BLOCKS), dim3(BLK), 0, stream, Pf);
        hipLaunchKernelGGL(sample_tg_k<__hip_bfloat16>, dim3(SAMP_BLOCKS), dim3(BLK), 0, stream, Pb);
    } else {
        hipLaunchKernelGGL(sample_k<float>, dim3(SAMP_BLOCKS), dim3(BLK), 0, stream, Pf);
        hipLaunchKernelGGL(sample_k<__hip_bfloat16>, dim3(SAMP_BLOCKS), dim3(BLK), 0, stream, Pb);
    }
    hipLaunchKernelGGL(composite_k<float>, dim3(NRAYS), dim3(64), 0, stream, Pf);
    hipLaunchKernelGGL(composite_k<__hip_bfloat16>, dim3(NRAYS), dim3(64), 0, stream, Pb);
}